// Round 4
// baseline (67.258 us; speedup 1.0000x reference)
//
#include <hip/hip_runtime.h>
#include <utility>

#define BATCH 32768
#define NPHI 35

typedef float v2f __attribute__((ext_vector_type(2)));

// ---------- compile-time combinatorics ----------
constexpr int choose2(int n){ return (n*(n-1))/2; }

constexpr int tri_id_sorted(int a,int b,int c){
  int id=0;
  for(int x=0;x<a;++x) id += choose2(6-x);
  for(int y=a+1;y<b;++y) id += (6-y);
  id += (c-b-1);
  return id;
}

constexpr int tri_id3(int a,int b,int c){
  int x=a,y=b,z=c;
  if (x>y){int t=x;x=y;y=t;}
  if (y>z){int t=y;y=z;z=t;}
  if (x>y){int t=x;x=y;y=t;}
  return tri_id_sorted(x,y,z);
}

constexpr int sgn3(int a,int b,int c){
  int inv = (a>b)+(a>c)+(b>c);
  return (inv&1)? -1 : 1;
}

constexpr int UT(int i,int j){
  return i*7 - (i*(i-1))/2 + (j-i);
}

constexpr int PAIR(int k,int l){
  return k*7 - (k*(k+1))/2 + (l - k - 1);
}

// ---------- straight-line build program (1470 fma-like ops) ----------
struct Prog {
  int n;
  unsigned char kind[1472];
  unsigned char init[1472];   // kind0 only: first write to dst
  short         dst [1472];
  unsigned char a   [1472];
  short         b   [1472];
  signed char   s   [1472];
  unsigned char grp [1472];   // kl group 0..20 (atomic per wave-phase)
};

constexpr Prog build_prog(){
  Prog P{}; P.n=0;
  for(int k=0;k<7;++k) for(int l=k+1;l<7;++l){
    const int kl = PAIR(k,l);
    bool tinit[7]={};
    // ---- T phase for this (k,l)
    for(int m=0;m<7;++m) for(int n2=m+1;n2<7;++n2){
      if(m==k||m==l||n2==k||n2==l) continue;
      int comp[3]={0,0,0}; int cn=0;
      for(int x=0;x<7;++x) if(x!=k&&x!=l&&x!=m&&x!=n2){ comp[cn]=x; ++cn; }
      int perm[7]={k,l,m,n2,comp[0],comp[1],comp[2]};
      int invc=0;
      for(int i=0;i<7;++i) for(int j=i+1;j<7;++j) if(perm[i]>perm[j]) ++invc;
      const int es=(invc&1)? -1 : 1;
      const int tcomp=tri_id_sorted(comp[0],comp[1],comp[2]);
      for(int j=0;j<7;++j){
        if(j==m||j==n2) continue;
        P.kind[P.n]=0;
        P.init[P.n]=tinit[j]?0:1; tinit[j]=true;
        P.dst [P.n]=(short)(kl*7+j);
        P.a   [P.n]=(unsigned char)tcomp;
        P.b   [P.n]=(short)tri_id3(j,m,n2);
        P.s   [P.n]=(signed char)(es*sgn3(j,m,n2));
        P.grp [P.n]=(unsigned char)kl;
        ++P.n;
      }
    }
    // ---- B phase for this (k,l): U always accumulated via fma (U pre-zeroed)
    for(int i=0;i<7;++i){
      if(i==k||i==l) continue;
      for(int j=i;j<7;++j){
        P.kind[P.n]=1;
        P.init[P.n]=0;
        P.dst [P.n]=(short)UT(i,j);
        P.a   [P.n]=(unsigned char)tri_id3(i,k,l);
        P.b   [P.n]=(short)(kl*7+j);
        P.s   [P.n]=(signed char)sgn3(i,k,l);
        P.grp [P.n]=(unsigned char)kl;
        ++P.n;
      }
    }
  }
  return P;
}

static constexpr Prog PROG = build_prog();
static_assert(PROG.n == 1470, "program size unexpected");

// Hand-balanced partition of the 21 kl groups over 4 waves.
// Group op-counts are 64+k+l; bins: ph0(main)=348, ph1=363, ph2=358, ph3=401.
// Main gets the smallest bin (it alone continues into Jacobi).
constexpr int PHASE_OF[21] = {
  3,3,3,3, 0, 1, 3,3, 0, 2, 1, 0, 0, 2, 2, 0, 2, 1, 2, 1, 1
};

// ---------- per-phase constant-index execution via fold expression ----------
template<int PH, int Q>
__device__ __forceinline__ void step_if(float (&T)[147], float (&U)[28],
                                        const float (&ph)[NPHI]){
  if constexpr (PHASE_OF[PROG.grp[Q]] == PH){
    if constexpr (Q > 0 && PROG.kind[Q] != PROG.kind[Q-1]) {
      __builtin_amdgcn_sched_barrier(0);
    }
    constexpr int  d = PROG.dst[Q];
    constexpr int  a = PROG.a[Q];
    constexpr int  b = PROG.b[Q];
    constexpr bool neg  = (PROG.s[Q] < 0);
    constexpr bool init = (PROG.init[Q] != 0);
    if constexpr (PROG.kind[Q] == 0){
      const float x = neg ? -ph[a] : ph[a];
      if constexpr (init) T[d] = x * ph[b];
      else                T[d] = fmaf(x, ph[b], T[d]);
    } else {
      const float x = neg ? -ph[a] : ph[a];
      U[d] = fmaf(x, T[b], U[d]);
    }
  }
}

template<int PH, int... Q>
__device__ __forceinline__ void run_phase(float (&T)[147], float (&U)[28],
                                          const float (&ph)[NPHI],
                                          std::integer_sequence<int, Q...>){
  (step_if<PH, Q>(T, U, ph), ...);
}

// one Jacobi rotation; GUARD compile-time: skip when ALL 64 lanes converged
// (perturbs eigenvalues by <= |apq| ~ 1e-6*scale — Weyl).
#define ROT_BODY(p1, q1, GUARD)                                               \
  {                                                                           \
    const float apq = A[UT(p1,q1)];                                           \
    const float app = A[UT(p1,p1)];                                           \
    const float aqq = A[UT(q1,q1)];                                           \
    bool doit = true;                                                         \
    if (GUARD) doit = __any(fabsf(apq) > 1e-6f*(fabsf(app)+fabsf(aqq)));      \
    if (doit) {                                                               \
      float d = 2.0f*apq;                                                     \
      d = d + ((d >= 0.0f)? 1e-30f : -1e-30f);                                \
      const float tau = (aqq - app) * __builtin_amdgcn_rcpf(d);               \
      float t = __builtin_amdgcn_rcpf(                                        \
                  fabsf(tau) + __builtin_amdgcn_sqrtf(fmaf(tau,tau,1.0f)));   \
      t = (tau >= 0.0f)? t : -t;                                              \
      const float c = __builtin_amdgcn_rsqf(fmaf(t,t,1.0f));                  \
      const float s = t*c;                                                    \
      A[UT(p1,p1)] = fmaf(-t, apq, app);                                      \
      A[UT(q1,q1)] = fmaf( t, apq, aqq);                                      \
      A[UT(p1,q1)] = 0.0f;                                                    \
      const v2f cs  = {  c, s };                                              \
      const v2f msc = { -s, c };                                              \
      _Pragma("unroll")                                                       \
      for (int r=0;r<7;++r){                                                  \
        if (r==p1 || r==q1) continue;                                         \
        const int irp = (r<p1)? UT(r,p1) : UT(p1,r);                          \
        const int irq = (r<q1)? UT(r,q1) : UT(q1,r);                          \
        const v2f arp2 = { A[irp], A[irp] };                                  \
        const v2f arq2 = { A[irq], A[irq] };                                  \
        const v2f res = __builtin_elementwise_fma(cs, arp2, msc*arq2);        \
        A[irp] = res.x;                                                       \
        A[irq] = res.y;                                                       \
      }                                                                       \
    }                                                                         \
  }

// ---------- kernel: 4 waves per 64 samples; 3 helper waves do 3/4 of the
// build on otherwise-idle SIMDs, main wave does 1/4 + reduce + Jacobi ----------
__global__ __launch_bounds__(256,2)
void PositivityConstraint_89086211654295_kernel(const float* __restrict__ phi,
                                                float* __restrict__ out){
  const int wv  = threadIdx.x >> 6;        // wave id 0..3 (0 = main)
  const int ln  = threadIdx.x & 63;        // lane / sample-within-block
  const int gid = blockIdx.x*64 + ln;      // BATCH == 512*64 exactly

  // partial-U staging: [helper][sample][30] (stride 30: 8B-aligned rows,
  // dword stride 30 → gcd(30,32)=2 → ~4-way worst-case bank aliasing, cheap)
  __shared__ float Upart[3][64][30];

  const float* __restrict__ p = phi + (size_t)gid * NPHI;
  float ph[NPHI];
  {
    const float4* __restrict__ p4 = reinterpret_cast<const float4*>(p);
    #pragma unroll
    for (int k=0;k<8;++k){
      const float4 v = p4[k];
      ph[4*k+0]=v.x; ph[4*k+1]=v.y; ph[4*k+2]=v.z; ph[4*k+3]=v.w;
    }
    ph[32]=p[32]; ph[33]=p[33]; ph[34]=p[34];
  }

  float T[147];
  float U[28];
  #pragma unroll
  for (int i=0;i<28;++i) U[i] = 0.0f;

  switch (wv){
    case 0: run_phase<0>(T,U,ph, std::make_integer_sequence<int,PROG.n>{}); break;
    case 1: run_phase<1>(T,U,ph, std::make_integer_sequence<int,PROG.n>{}); break;
    case 2: run_phase<2>(T,U,ph, std::make_integer_sequence<int,PROG.n>{}); break;
    default:run_phase<3>(T,U,ph, std::make_integer_sequence<int,PROG.n>{}); break;
  }

  if (wv){
    v2f* __restrict__ row = reinterpret_cast<v2f*>(&Upart[wv-1][ln][0]);
    #pragma unroll
    for (int k=0;k<14;++k){ v2f t = { U[2*k], U[2*k+1] }; row[k] = t; }
  }
  __syncthreads();
  if (wv) return;

  // main: accumulate helper partials
  #pragma unroll
  for (int h=0;h<3;++h){
    const v2f* __restrict__ row = reinterpret_cast<const v2f*>(&Upart[h][ln][0]);
    #pragma unroll
    for (int k=0;k<14;++k){
      const v2f t = row[k];
      U[2*k]   += t.x;
      U[2*k+1] += t.y;
    }
  }

  float A[28];
  #pragma unroll
  for (int i=0;i<28;++i) A[i] = U[i]*(1.0f/6.0f);

  // Cyclic Jacobi: 4 full sweeps + 1 skip-guarded polish pass (round-3 form,
  // known absmax 2.0 — unchanged this round).
  #pragma unroll 1
  for (int sweep=0; sweep<4; ++sweep){
    #pragma unroll
    for (int p1=0;p1<7;++p1){
      #pragma unroll
      for (int q1=p1+1;q1<7;++q1){
        ROT_BODY(p1, q1, false)
      }
    }
  }
  { // polish pass
    #pragma unroll
    for (int p1=0;p1<7;++p1){
      #pragma unroll
      for (int q1=p1+1;q1<7;++q1){
        ROT_BODY(p1, q1, true)
      }
    }
  }

  // det(B) = product of eigenvalues; eig(g) = eig(B) / (|det|+1e-12)^(1/9)
  float det = 1.0f;
  #pragma unroll
  for (int i=0;i<7;++i) det *= A[UT(i,i)];
  const float ad = fabsf(det) + 1e-12f;
  const float scale = __builtin_amdgcn_exp2f(__builtin_amdgcn_logf(ad) * (1.0f/9.0f));
  const float inv = __builtin_amdgcn_rcpf(scale);

  float sum = 0.0f;
  #pragma unroll
  for (int i=0;i<7;++i){
    const float ev = A[UT(i,i)]*inv;
    const float r = 1e-6f - ev;
    sum += fmaxf(r, 0.0f);
  }
  out[gid] = sum;
}

// ---------- launch ----------
extern "C" void kernel_launch(void* const* d_in, const int* in_sizes, int n_in,
                              void* d_out, int out_size, void* d_ws, size_t ws_size,
                              hipStream_t stream) {
  const float* phi = (const float*)d_in[0];
  float* out = (float*)d_out;
  (void)in_sizes; (void)n_in; (void)out_size; (void)d_ws; (void)ws_size;
  hipLaunchKernelGGL(PositivityConstraint_89086211654295_kernel,
                     dim3(BATCH/64), dim3(256), 0, stream, phi, out);
}

// Round 6
// 62.422 us; speedup vs baseline: 1.0775x; 1.0775x over previous
//
#include <hip/hip_runtime.h>
#include <utility>

#define BATCH 32768
#define NPHI 35

typedef float v2f __attribute__((ext_vector_type(2)));

// ---------- compile-time combinatorics ----------
constexpr int choose2(int n){ return (n*(n-1))/2; }

constexpr int tri_id_sorted(int a,int b,int c){
  int id=0;
  for(int x=0;x<a;++x) id += choose2(6-x);
  for(int y=a+1;y<b;++y) id += (6-y);
  id += (c-b-1);
  return id;
}

constexpr int tri_id3(int a,int b,int c){
  int x=a,y=b,z=c;
  if (x>y){int t=x;x=y;y=t;}
  if (y>z){int t=y;y=z;z=t;}
  if (x>y){int t=x;x=y;y=t;}
  return tri_id_sorted(x,y,z);
}

constexpr int sgn3(int a,int b,int c){
  int inv = (a>b)+(a>c)+(b>c);
  return (inv&1)? -1 : 1;
}

constexpr int UT(int i,int j){
  return i*7 - (i*(i-1))/2 + (j-i);
}

constexpr int PAIR(int k,int l){
  return k*7 - (k*(k+1))/2 + (l - k - 1);
}

// ---------- the straight-line "program": 1470 fma-like ops ----------
struct Prog {
  int n;
  unsigned char kind[1472];
  unsigned char init[1472];   // 1 = first write to dst (use mul, not fma)
  short         dst [1472];
  unsigned char a   [1472];
  short         b   [1472];
  signed char   s   [1472];
};

constexpr Prog build_prog(){
  Prog P{}; P.n=0;
  bool uinit[28]={};
  for(int k=0;k<7;++k) for(int l=k+1;l<7;++l){
    const int kl = PAIR(k,l);
    bool tinit[7]={};
    // ---- T phase for this (k,l)
    for(int m=0;m<7;++m) for(int n2=m+1;n2<7;++n2){
      if(m==k||m==l||n2==k||n2==l) continue;
      int comp[3]={0,0,0}; int cn=0;
      for(int x=0;x<7;++x) if(x!=k&&x!=l&&x!=m&&x!=n2){ comp[cn]=x; ++cn; }
      int perm[7]={k,l,m,n2,comp[0],comp[1],comp[2]};
      int invc=0;
      for(int i=0;i<7;++i) for(int j=i+1;j<7;++j) if(perm[i]>perm[j]) ++invc;
      const int es=(invc&1)? -1 : 1;
      const int tcomp=tri_id_sorted(comp[0],comp[1],comp[2]);
      for(int j=0;j<7;++j){
        if(j==m||j==n2) continue;
        P.kind[P.n]=0;
        P.init[P.n]=tinit[j]?0:1; tinit[j]=true;
        P.dst [P.n]=(short)(kl*7+j);
        P.a   [P.n]=(unsigned char)tcomp;
        P.b   [P.n]=(short)tri_id3(j,m,n2);
        P.s   [P.n]=(signed char)(es*sgn3(j,m,n2));
        ++P.n;
      }
    }
    // ---- B phase for this (k,l)
    for(int i=0;i<7;++i){
      if(i==k||i==l) continue;
      for(int j=i;j<7;++j){
        P.kind[P.n]=1;
        P.init[P.n]=uinit[UT(i,j)]?0:1; uinit[UT(i,j)]=true;
        P.dst [P.n]=(short)UT(i,j);
        P.a   [P.n]=(unsigned char)tri_id3(i,k,l);
        P.b   [P.n]=(short)(kl*7+j);
        P.s   [P.n]=(signed char)sgn3(i,k,l);
        ++P.n;
      }
    }
  }
  return P;
}

static constexpr Prog PROG = build_prog();
static_assert(PROG.n == 1470, "program size unexpected");

// ---------- guaranteed-constant-index execution via fold expression ----------
template<int Q>
__device__ __forceinline__ void step(float (&T)[147], float (&U)[28],
                                     const float (&ph)[NPHI]){
  if constexpr (Q > 0 && PROG.kind[Q] != PROG.kind[Q-1]) {
    __builtin_amdgcn_sched_barrier(0);
  }
  constexpr int  d = PROG.dst[Q];
  constexpr int  a = PROG.a[Q];
  constexpr int  b = PROG.b[Q];
  constexpr bool neg  = (PROG.s[Q] < 0);
  constexpr bool init = (PROG.init[Q] != 0);
  if constexpr (PROG.kind[Q] == 0){
    const float x = neg ? -ph[a] : ph[a];
    if constexpr (init) T[d] = x * ph[b];
    else                T[d] = fmaf(x, ph[b], T[d]);
  } else {
    const float x = neg ? -ph[a] : ph[a];
    if constexpr (init) U[d] = x * T[b];
    else                U[d] = fmaf(x, T[b], U[d]);
  }
}

template<int... Q>
__device__ __forceinline__ void run_prog(float (&T)[147], float (&U)[28],
                                         const float (&ph)[NPHI],
                                         std::integer_sequence<int, Q...>){
  (step<Q>(T, U, ph), ...);
}

// one Jacobi rotation — half-angle c,s + BASELINE-EXACT diagonal update.
//   x = aqq−app, y = 2·apq, r = √(x²+y²)
//   t = sgn(x)·sgn(y)·|y|/(|x|+r)     ≡ baseline sign(tau)/(|tau|+√(1+tau²))
//   u = |x|/r = cos2θ ;  c = √((1+u)/2) ;  s = t·c
//   diag: app' = app − t·apq, aqq' = aqq + t·apq   (identical to baseline —
//   the R5 failure was the avg±m1 diag form, not the half-angle c,s)
// Serial transcendental depth 2: rsq → {sqrt ∥ rcp}. ax=|x|+1e-18 keeps ax²
// normal (≥1e-36) so x=y=0 → u=1,c=1,t=s=0 (exact identity), no NaN.
// GUARD compile-time: skip when ALL 64 lanes converged (Weyl: perturbs
// eigenvalues by <= |apq| ~ 1e-6*scale).
#define ROT_BODY(p1, q1, GUARD)                                               \
  {                                                                           \
    const float apq = A[UT(p1,q1)];                                           \
    const float app = A[UT(p1,p1)];                                           \
    const float aqq = A[UT(q1,q1)];                                           \
    bool doit = true;                                                         \
    if (GUARD) doit = __any(fabsf(apq) > 1e-6f*(fabsf(app)+fabsf(aqq)));      \
    if (doit) {                                                               \
      const float x   = aqq - app;                                            \
      const float y   = apq + apq;                                            \
      const float ax  = fabsf(x) + 1e-18f;                                    \
      const float ss  = fmaf(ax, ax, y*y);         /* r^2, normal */          \
      const float w   = __builtin_amdgcn_rsqf(ss); /* 1/r */                  \
      const float u   = ax * w;                    /* cos2t in (0,1] */       \
      const float r1  = ss * w;                    /* r = sqrt(ss) */         \
      const float c   = __builtin_amdgcn_sqrtf(fmaf(0.5f, u, 0.5f));          \
      const float tm  = fabsf(y) * __builtin_amdgcn_rcpf(ax + r1); /* |t| */  \
      const unsigned sb = (__float_as_uint(x) ^ __float_as_uint(y))           \
                          & 0x80000000u;                                      \
      const float t   = __uint_as_float(__float_as_uint(tm) ^ sb);            \
      const float s1  = t * c;                                                \
      A[UT(p1,p1)] = fmaf(-t, apq, app);                                      \
      A[UT(q1,q1)] = fmaf( t, apq, aqq);                                      \
      A[UT(p1,q1)] = 0.0f;                                                    \
      const v2f cs2 = {  c, s1 };                                             \
      const v2f msc = { -s1, c };                                             \
      _Pragma("unroll")                                                       \
      for (int r=0;r<7;++r){                                                  \
        if (r==p1 || r==q1) continue;                                         \
        const int irp = (r<p1)? UT(r,p1) : UT(p1,r);                          \
        const int irq = (r<q1)? UT(r,q1) : UT(q1,r);                          \
        const v2f arp2 = { A[irp], A[irp] };                                  \
        const v2f arq2 = { A[irq], A[irq] };                                  \
        const v2f res = __builtin_elementwise_fma(cs2, arp2, msc*arq2);       \
        A[irp] = res.x;                                                       \
        A[irq] = res.y;                                                       \
      }                                                                       \
    }                                                                         \
  }

// ---------- kernel (R3 launch shape: 64-thread blocks, 1 wave) ----------
__global__ __launch_bounds__(64,1)
void PositivityConstraint_89086211654295_kernel(const float* __restrict__ phi,
                                                float* __restrict__ out){
  const int gid = blockIdx.x*64 + threadIdx.x;   // BATCH == 512*64 exactly

  const float* __restrict__ p = phi + (size_t)gid * NPHI;
  float ph[NPHI];
  // vectorized input: 8 x dwordx4 + 3 x dword
  {
    const float4* __restrict__ p4 = reinterpret_cast<const float4*>(p);
    #pragma unroll
    for (int k=0;k<8;++k){
      const float4 v = p4[k];
      ph[4*k+0]=v.x; ph[4*k+1]=v.y; ph[4*k+2]=v.z; ph[4*k+3]=v.w;
    }
    ph[32]=p[32]; ph[33]=p[33]; ph[34]=p[34];
  }

  float T[147];   // scalarized by constant indexing; short live ranges
  float U[28];
  run_prog(T, U, ph, std::make_integer_sequence<int, PROG.n>{});
  __builtin_amdgcn_sched_barrier(0);

  float A[28];
  #pragma unroll
  for (int i=0;i<28;++i) A[i] = U[i]*(1.0f/6.0f);

  // Cyclic Jacobi: 4 full sweeps + 1 skip-guarded polish pass
  // (R3 structure verbatim; only the rotation-parameter math changed).
  #pragma unroll 1
  for (int sweep=0; sweep<4; ++sweep){
    #pragma unroll
    for (int p1=0;p1<7;++p1){
      #pragma unroll
      for (int q1=p1+1;q1<7;++q1){
        ROT_BODY(p1, q1, false)
      }
    }
  }
  { // polish pass
    #pragma unroll
    for (int p1=0;p1<7;++p1){
      #pragma unroll
      for (int q1=p1+1;q1<7;++q1){
        ROT_BODY(p1, q1, true)
      }
    }
  }

  // det(B) = product of eigenvalues; eig(g) = eig(B) / (|det|+1e-12)^(1/9)
  float det = 1.0f;
  #pragma unroll
  for (int i=0;i<7;++i) det *= A[UT(i,i)];
  const float ad = fabsf(det) + 1e-12f;
  const float scale = __builtin_amdgcn_exp2f(__builtin_amdgcn_logf(ad) * (1.0f/9.0f));
  const float inv = __builtin_amdgcn_rcpf(scale);

  float sum = 0.0f;
  #pragma unroll
  for (int i=0;i<7;++i){
    const float ev = A[UT(i,i)]*inv;
    const float r = 1e-6f - ev;
    sum += fmaxf(r, 0.0f);
  }
  out[gid] = sum;
}

// ---------- launch ----------
extern "C" void kernel_launch(void* const* d_in, const int* in_sizes, int n_in,
                              void* d_out, int out_size, void* d_ws, size_t ws_size,
                              hipStream_t stream) {
  const float* phi = (const float*)d_in[0];
  float* out = (float*)d_out;
  (void)in_sizes; (void)n_in; (void)out_size; (void)d_ws; (void)ws_size;
  hipLaunchKernelGGL(PositivityConstraint_89086211654295_kernel,
                     dim3(BATCH/64), dim3(64), 0, stream, phi, out);
}